// Round 5
// baseline (1317.238 us; speedup 1.0000x reference)
//
#include <hip/hip_runtime.h>
#include <math.h>

#define TS 10
#define TD 128
#define TE 64
#define BT 8
#define NTHR 256
#define HSTR 132          // floats per Hs row: 128+4 pad
#define QSTR 68           // floats per Q/K/Vd/G/t row: 64+4 pad
#define NHROWS (TS*BT)    // 80

#define HS_FLOATS (NHROWS*HSTR)    // 10560
#define BUF_FLOATS (40*QSTR)       // 2720 (half-batch 40-row buffer)
#define P_FLOATS (BT*TS*12)        // 960
#define LDS_FLOATS (HS_FLOATS + 3*BUF_FLOATS + P_FLOATS)   // 19680 -> 78720 B (2 WG/CU)

#define INVSQRT10 0.31622776601683794f

typedef float v2f __attribute__((ext_vector_type(2)));

// ---------------- POS precompute (fp64, once per launch, into d_ws) ----------
__global__ void pos_kernel(float* __restrict__ pos) {
    for (int idx = threadIdx.x; idx < TS * TD; idx += blockDim.x) {
        int n = idx / TD, d = idx % TD;
        int j = d >> 1;
        double ang = (double)n / pow(1000.0, 2.0 * (double)j / (double)TD);
        double v = (d & 1) ? cos(ang) : sin(ang);
        pos[idx] = (float)v;
    }
}

// ---------------- M-row x C-col fp32 GEMM tile, packed-pair FMAs ------------
// OUT[m][c] = sum_k A[row(m)+k] * W[k*ws+c]. A,O in LDS; W in global.
// K multiple of 16. DEEP W-PREFETCH (R5): W is loaded a full 8-k iteration
// (~256 compute-cycles for M=8/C=4) before first use — covering the ~200+cyc
// L2-hit latency that the old 4-k (128cyc) distance exposed at every chunk
// boundary (R0: 38% VALU-idle with only 2 barrier-locked waves/SIMD).
// A stays at a 4-k double-buffer (LDS latency ~120 <= 128cyc cover).
// VGPR: acc 2*M + A 2*4*M + W 2*32*CG + addr ~= 160 for M=8/C=4 — still
// 8 waves/CU per the measured 64/128/256 occupancy steps.
template <int M, int SPLIT, int C, int K, bool ADD>
__device__ __forceinline__ void gemm_f32(
    const float* __restrict__ Ap, int a0, int aHi, int aLo,
    const float* __restrict__ W, int ws,
    float* __restrict__ Op, int o0, int oHi, int oLo,
    float scale)
{
    static_assert(C % 4 == 0, "C must be a multiple of 4");
    static_assert(K % 16 == 0 && K >= 32, "K must be a multiple of 16, >=32");
    constexpr int CG = C / 4;   // float4 groups
    constexpr int CP = C / 2;   // float2 pairs
    v2f acc[M][CP];
#pragma unroll
    for (int m = 0; m < M; m++)
#pragma unroll
        for (int p = 0; p < CP; p++) acc[m][p] = (v2f)(0.f);

    float4 aR0[M], aR1[M];
    float4 wA[8 * CG], wB[8 * CG];      // ping-pong 8-k W buffers
    const float* ap = Ap + a0;
    const float* wp = W;

    auto loadW8 = [&](float4* wR, const float* w) {
#pragma unroll
        for (int kk = 0; kk < 8; kk++)
#pragma unroll
            for (int cg = 0; cg < CG; cg++)
                wR[kk * CG + cg] = *(const float4*)(w + kk * ws + cg * 4);
    };
    auto loadA = [&](float4* aR, const float* a) {
#pragma unroll
        for (int m = 0; m < M; m++)
            aR[m] = *(const float4*)(a + (m / SPLIT) * aHi + (m % SPLIT) * aLo);
    };
    // 4 consecutive k-steps from wR[0..4*CG)
    auto computeH = [&](const float4* aR, const float4* wR) {
#pragma unroll
        for (int m = 0; m < M; m++) {
            const float* af = (const float*)&aR[m];
#pragma unroll
            for (int kk = 0; kk < 4; kk++) {
                v2f av; av.x = af[kk]; av.y = af[kk];
                const v2f* wf = (const v2f*)&wR[kk * CG];
#pragma unroll
                for (int p = 0; p < CP; p++)
                    acc[m][p] = av * wf[p] + acc[m][p];   // v_pk_fma_f32
            }
        }
    };

    loadW8(wA, wp);          // k rows 0..7
    loadA(aR0, ap);          // k 0..3
#pragma unroll 1
    for (int k = 0; k + 16 < K; k += 16) {
        loadW8(wB, wp + 8 * ws);        // rows k+8..k+15 (used 2 computeH later)
        loadA(aR1, ap + 4);             // k+4..7
        computeH(aR0, wA);              // k..k+3
        loadA(aR0, ap + 8);             // k+8..11
        computeH(aR1, wA + 4 * CG);     // k+4..7
        loadW8(wA, wp + 16 * ws);       // rows k+16..k+23 (next iter / tail)
        loadA(aR1, ap + 12);            // k+12..15
        computeH(aR0, wB);              // k+8..11
        loadA(aR0, ap + 16);            // k+16..19
        computeH(aR1, wB + 4 * CG);     // k+12..15
        wp += 16 * ws; ap += 16;
    }
    // tail: final 16 k-steps (wA = rows k..k+7, aR0 = k..k+3)
    loadW8(wB, wp + 8 * ws);
    loadA(aR1, ap + 4);
    computeH(aR0, wA);
    loadA(aR0, ap + 8);
    computeH(aR1, wA + 4 * CG);
    loadA(aR1, ap + 12);
    computeH(aR0, wB);
    computeH(aR1, wB + 4 * CG);

    v2f s2; s2.x = scale; s2.y = scale;
#pragma unroll
    for (int m = 0; m < M; m++) {
        float* op = Op + o0 + (m / SPLIT) * oHi + (m % SPLIT) * oLo;
#pragma unroll
        for (int cg = 0; cg < CG; cg++) {
            float4 r;
            v2f* rp = (v2f*)&r;
            if constexpr (ADD) {
                float4 v = *(float4*)(op + cg * 4);
                const v2f* vp = (const v2f*)&v;
                rp[0] = s2 * acc[m][cg * 2 + 0] + vp[0];
                rp[1] = s2 * acc[m][cg * 2 + 1] + vp[1];
            } else {
                rp[0] = s2 * acc[m][cg * 2 + 0];
                rp[1] = s2 * acc[m][cg * 2 + 1];
            }
            *(float4*)(op + cg * 4) = r;
        }
    }
}

// ---------------- fused kernel ----------------------------------------------
// BT=8, hb-split, 78.72 KB LDS -> 2 WG/CU (LDS-limited). launch_bounds(256,1):
// empirical VGPR caps are arg2->cap {1:256, 2:128, 4:64}; the deep-prefetch
// gemm needs ~160 VGPR, and VGPR 129..256 still sustains 8 waves/CU
// (occupancy steps at 64/128/256) — so 2 WG/CU residency is preserved.
extern "C" __global__ __launch_bounds__(NTHR, 1)
void trans_fused(const float* __restrict__ x,
                 const float* __restrict__ L_w, const float* __restrict__ UL_w,
                 const float* __restrict__ WQ,  const float* __restrict__ WK,
                 const float* __restrict__ WVd, const float* __restrict__ WVu,
                 const float* __restrict__ WQ2, const float* __restrict__ WK2,
                 const float* __restrict__ WVd2,const float* __restrict__ WVu2,
                 const float* __restrict__ qin1,const float* __restrict__ qout1,
                 const float* __restrict__ qin2,const float* __restrict__ qout2,
                 const float* __restrict__ POSb, float* __restrict__ out)
{
    extern __shared__ float lds[];
    float* Hs = lds;                      // [80][HSTR], row = b*10 + n
    float* Qb = lds + HS_FLOATS;          // [40][QSTR], row r2 = b4*10 + n ; also G, t(lo)
    float* Kb = Qb + BUF_FLOATS;          // [40][QSTR]                     ; also t(hi)
    float* Vb = Kb + BUF_FLOATS;          // [40][QSTR] Vd
    float* Pb = Vb + BUF_FLOATS;          // [8][10][12] logits -> softmax weights
    float* Tb = Qb;                       // t: 80 rows spanning Qb+Kb

    const int tid = threadIdx.x;
    const int vtid = (tid + ((blockIdx.x & 3) << 6)) & 255;  // rotate idle windows
    const int gb0 = blockIdx.x * BT;

    // ---- Phase 0: h = x @ L_w + POS (fp32; 4-term dot, packed) ----
    for (int idx = tid; idx < NHROWS * 32; idx += NTHR) {
        int r = idx >> 5, dg = (idx & 31) << 2;
        int b = r / 10, n = r - b * 10;
        const float* xp = x + ((size_t)(gb0 + b) * TS + n) * 4;
        float4 xv = *(const float4*)xp;
        const float* xf = (const float*)&xv;
        float4 p4 = *(const float4*)(POSb + n * TD + dg);
        v2f acc0 = ((const v2f*)&p4)[0], acc1 = ((const v2f*)&p4)[1];
#pragma unroll
        for (int c = 0; c < 4; c++) {
            float4 lw = *(const float4*)(L_w + c * TD + dg);
            v2f xb; xb.x = xf[c]; xb.y = xf[c];
            acc0 = xb * ((const v2f*)&lw)[0] + acc0;
            acc1 = xb * ((const v2f*)&lw)[1] + acc1;
        }
        float4 r4;
        ((v2f*)&r4)[0] = acc0; ((v2f*)&r4)[1] = acc1;
        *(float4*)(Hs + r * HSTR + dg) = r4;
    }
    __syncthreads();

    for (int layer = 0; layer < 2; ++layer) {
        const float* pWQ  = layer ? WQ2  : WQ;
        const float* pWK  = layer ? WK2  : WK;
        const float* pWVd = layer ? WVd2 : WVd;
        const float* pWVu = layer ? WVu2 : WVu;
        const float* pqin = layer ? qin2 : qin1;
        const float* pqou = layer ? qout2 : qout1;

        for (int hb = 0; hb < 2; ++hb) {
            // batches b = hb*4 + b4; Hs rows (hb*4+b4)*10 + n
            // ---- QKV: 240 tasks = mat(3) x np(5) x cg(16); M=8 = b4(4) x (n,n+5) ----
            if (vtid < 240) {
                int p = vtid / 80, t2 = vtid % 80;
                int np = t2 >> 4, cg = t2 & 15;
                const float* Wp = (p == 0 ? pWQ : (p == 1 ? pWK : pWVd)) + cg * 4;
                float* Ob = (p == 0 ? Qb : (p == 1 ? Kb : Vb));
                gemm_f32<8, 2, 4, TD, false>(
                    Hs, (hb * 40 + np) * HSTR, 10 * HSTR, 5 * HSTR,
                    Wp, TE,
                    Ob, np * QSTR + cg * 4, 10 * QSTR, 5 * QSTR, 1.f);
            }
            __syncthreads();

            // ---- logits (fp32, 2x2 packed chains): 220 = b4(4) x 55 (i,j<=i) ----
            if (vtid < 220) {
                int b4 = vtid / 55, pr = vtid % 55;
                int i = 0, base = 0;
                while (pr >= base + i + 1) { base += i + 1; i++; }
                int j = pr - base;
                const float* qr = Qb + (b4 * 10 + i) * QSTR;
                const float* kr = Kb + (b4 * 10 + j) * QSTR;
                v2f s0 = (v2f)(0.f), s1 = (v2f)(0.f);
                for (int e = 0; e < TE; e += 8) {
                    float4 qa = *(const float4*)(qr + e);
                    float4 ka = *(const float4*)(kr + e);
                    float4 qc = *(const float4*)(qr + e + 4);
                    float4 kc = *(const float4*)(kr + e + 4);
                    s0 = ((const v2f*)&qa)[0] * ((const v2f*)&ka)[0] + s0;
                    s1 = ((const v2f*)&qa)[1] * ((const v2f*)&ka)[1] + s1;
                    s0 = ((const v2f*)&qc)[0] * ((const v2f*)&kc)[0] + s0;
                    s1 = ((const v2f*)&qc)[1] * ((const v2f*)&kc)[1] + s1;
                }
                Pb[(hb * 4 + b4) * 120 + i * 12 + j] = (s0.x + s0.y) + (s1.x + s1.y);
            }
            __syncthreads();

            // ---- softmax over keys j<=i (fp32, matches reference) ----
            if (vtid < 40) {
                int b4 = vtid / 10, i = vtid % 10;
                float* pr = Pb + (hb * 4 + b4) * 120 + i * 12;
                float m = pr[0];
#pragma unroll
                for (int j = 1; j < TS; j++) if (j <= i) m = fmaxf(m, pr[j]);
                float sum = 0.f;
#pragma unroll
                for (int j = 0; j < TS; j++) if (j <= i) { float e = expf(pr[j] - m); pr[j] = e; sum += e; }
#pragma unroll
                for (int j = 0; j < TS; j++) pr[j] = (j <= i) ? pr[j] / sum : 0.f;
            }
            __syncthreads();

            // ---- G[r2=b4*10+q][e] = sum_k P * Vd[b4*10+k][e]; into Qb (Q dead) ----
            for (int oi = vtid; oi < 40 * 16; oi += NTHR) {
                int rr = oi >> 4, e4 = (oi & 15) * 4;
                int b4 = rr / 10, q = rr - b4 * 10;
                const float* pp = Pb + (hb * 4 + b4) * 120 + q * 12;
                v2f g0 = (v2f)(0.f), g1 = (v2f)(0.f);
#pragma unroll
                for (int k = 0; k < TS; k++) {
                    float p = pp[k];
                    v2f pv; pv.x = p; pv.y = p;
                    float4 v = *(const float4*)(Vb + (b4 * 10 + k) * QSTR + e4);
                    g0 = pv * ((const v2f*)&v)[0] + g0;
                    g1 = pv * ((const v2f*)&v)[1] + g1;
                }
                float4 g;
                ((v2f*)&g)[0] = g0; ((v2f*)&g)[1] = g1;
                *(float4*)(Qb + rr * QSTR + e4) = g;
            }
            __syncthreads();

            // ---- DE: Hs(half) += invsqrt10 * G @ WVu ----
            // 256 tasks exactly: b4(4) x qp(2) x cg(32); M=5 contiguous q rows.
            {
                int b4 = vtid >> 6, t2 = vtid & 63;
                int qp = t2 >> 5, cg = t2 & 31;
                gemm_f32<5, 5, 4, TE, true>(
                    Qb, (b4 * 10 + qp * 5) * QSTR, 0, QSTR,
                    pWVu + cg * 4, TD,
                    Hs, (hb * 40 + b4 * 10 + qp * 5) * HSTR + cg * 4, 0, HSTR,
                    INVSQRT10);
            }
            __syncthreads();
        } // hb

        // ---- ques-in: t[80][64] = Hs @ quesin[n]; 160 = n(10) x cg(16), M=8 over b ----
        if (vtid < 160) {
            int n = vtid >> 4, cg = vtid & 15;
            gemm_f32<8, 1, 4, TD, false>(
                Hs, n * HSTR, 10 * HSTR, 0,
                pqin + (size_t)n * TD * TE + cg * 4, TE,
                Tb, n * QSTR + cg * 4, 10 * QSTR, 0, 1.f);
        }
        __syncthreads();

        // ---- ques-out: Hs = t @ quesout[n]; 320 = n(10) x cg(32), M=8 C=4 ----
        for (int task = vtid; task < 320; task += NTHR) {
            int n = task >> 5, cg = task & 31;
            gemm_f32<8, 1, 4, TE, false>(
                Tb, n * QSTR, 10 * QSTR, 0,
                pqou + (size_t)n * TE * TD + cg * 4, TD,
                Hs, n * HSTR + cg * 4, 10 * HSTR, 0, 1.f);
        }
        __syncthreads();
    } // layer

    // ---- out = Hs @ UL_w : 320 outs, rotated grid-stride ----
    for (int idx = vtid; idx < NHROWS * 4; idx += NTHR) {
        int r = idx >> 2, c = idx & 3;
        int b = r / 10, n = r - b * 10;
        const float* hr = Hs + r * HSTR;
        float acc = 0.f;
        for (int d = 0; d < TD; d += 4) {
            float4 h4 = *(const float4*)(hr + d);
            acc = fmaf(h4.x, UL_w[(d + 0) * 4 + c], acc);
            acc = fmaf(h4.y, UL_w[(d + 1) * 4 + c], acc);
            acc = fmaf(h4.z, UL_w[(d + 2) * 4 + c], acc);
            acc = fmaf(h4.w, UL_w[(d + 3) * 4 + c], acc);
        }
        out[((size_t)(gb0 + b) * TS + n) * 4 + c] = acc;
    }
}

// ---------------- host launch -----------------------------------------------
extern "C" void kernel_launch(void* const* d_in, const int* in_sizes, int n_in,
                              void* d_out, int out_size, void* d_ws, size_t ws_size,
                              hipStream_t stream) {
    const float* x    = (const float*)d_in[0];
    const float* L_w  = (const float*)d_in[1];
    const float* UL_w = (const float*)d_in[2];
    const float* WQ   = (const float*)d_in[3];
    const float* WK   = (const float*)d_in[4];
    const float* WVd  = (const float*)d_in[5];
    const float* WVu  = (const float*)d_in[6];
    const float* WQ2  = (const float*)d_in[7];
    const float* WK2  = (const float*)d_in[8];
    const float* WVd2 = (const float*)d_in[9];
    const float* WVu2 = (const float*)d_in[10];
    const float* qin1 = (const float*)d_in[11];
    const float* qout1= (const float*)d_in[12];
    const float* qin2 = (const float*)d_in[13];
    const float* qout2= (const float*)d_in[14];
    float* out = (float*)d_out;
    float* POSb = (float*)d_ws;

    int B = in_sizes[0] / (TS * 4);
    size_t lds_bytes = (size_t)LDS_FLOATS * sizeof(float);

    (void)hipFuncSetAttribute((const void*)trans_fused,
                              hipFuncAttributeMaxDynamicSharedMemorySize,
                              (int)lds_bytes);

    pos_kernel<<<dim3(1), dim3(256), 0, stream>>>(POSb);
    trans_fused<<<dim3(B / BT), dim3(NTHR), lds_bytes, stream>>>(
        x, L_w, UL_w, WQ, WK, WVd, WVu, WQ2, WK2, WVd2, WVu2,
        qin1, qout1, qin2, qout2, POSb, out);
}

// Round 6
// 1035.679 us; speedup vs baseline: 1.2719x; 1.2719x over previous
//
#include <hip/hip_runtime.h>
#include <math.h>

#define TS 10
#define TD 128
#define TE 64
#define BT 8
#define NTHR 256
#define HSTR 132          // floats per Hs row: 128+4 pad
#define QSTR 68           // floats per Q/K/Vd/G/t row: 64+4 pad
#define NHROWS (TS*BT)    // 80

#define HS_FLOATS (NHROWS*HSTR)    // 10560
#define BUF_FLOATS (40*QSTR)       // 2720 (half-batch 40-row buffer)
#define P_FLOATS (BT*TS*12)        // 960
#define LDS_FLOATS (HS_FLOATS + 3*BUF_FLOATS + P_FLOATS)   // 19680 -> 78720 B (2 WG/CU)

#define INVSQRT10 0.31622776601683794f

typedef float v2f __attribute__((ext_vector_type(2)));

// ---------------- POS precompute (fp64, once per launch, into d_ws) ----------
__global__ void pos_kernel(float* __restrict__ pos) {
    for (int idx = threadIdx.x; idx < TS * TD; idx += blockDim.x) {
        int n = idx / TD, d = idx % TD;
        int j = d >> 1;
        double ang = (double)n / pow(1000.0, 2.0 * (double)j / (double)TD);
        double v = (d & 1) ? cos(ang) : sin(ang);
        pos[idx] = (float)v;
    }
}

// ---------------- M-row x C-col fp32 GEMM tile, packed-pair FMAs ------------
// OUT[m][c] = sum_k A[row(m)+k] * W[k*ws+c]. A,O in LDS; W in global.
// K multiple of 16. Deep W-prefetch: W loads issue a full 8-k block (~256
// compute-cycles at M=8/C=4) before first use, covering the ~200cyc L2-hit
// latency that a 4-k distance exposes (R0: 62% VALUBusy cap == 128/200).
// A stays at a 4-k double-buffer (LDS ~120cyc <= 128cyc cover).
// R6: compiled under a hard 128-VGPR cap (launch_bounds 2nd arg = 2) so the
// 2-WG/CU residency survives; R5 measured 132 VGPR -> occupancy halved.
template <int M, int SPLIT, int C, int K, bool ADD>
__device__ __forceinline__ void gemm_f32(
    const float* __restrict__ Ap, int a0, int aHi, int aLo,
    const float* __restrict__ W, int ws,
    float* __restrict__ Op, int o0, int oHi, int oLo,
    float scale)
{
    static_assert(C % 4 == 0, "C must be a multiple of 4");
    static_assert(K % 16 == 0 && K >= 32, "K must be a multiple of 16, >=32");
    constexpr int CG = C / 4;   // float4 groups
    constexpr int CP = C / 2;   // float2 pairs
    v2f acc[M][CP];
#pragma unroll
    for (int m = 0; m < M; m++)
#pragma unroll
        for (int p = 0; p < CP; p++) acc[m][p] = (v2f)(0.f);

    float4 aR0[M], aR1[M];
    float4 wA[8 * CG], wB[8 * CG];      // ping-pong 8-k W buffers
    const float* ap = Ap + a0;
    const float* wp = W;

    auto loadW8 = [&](float4* wR, const float* w) {
#pragma unroll
        for (int kk = 0; kk < 8; kk++)
#pragma unroll
            for (int cg = 0; cg < CG; cg++)
                wR[kk * CG + cg] = *(const float4*)(w + kk * ws + cg * 4);
    };
    auto loadA = [&](float4* aR, const float* a) {
#pragma unroll
        for (int m = 0; m < M; m++)
            aR[m] = *(const float4*)(a + (m / SPLIT) * aHi + (m % SPLIT) * aLo);
    };
    // 4 consecutive k-steps from wR[0..4*CG)
    auto computeH = [&](const float4* aR, const float4* wR) {
#pragma unroll
        for (int m = 0; m < M; m++) {
            const float* af = (const float*)&aR[m];
#pragma unroll
            for (int kk = 0; kk < 4; kk++) {
                v2f av; av.x = af[kk]; av.y = af[kk];
                const v2f* wf = (const v2f*)&wR[kk * CG];
#pragma unroll
                for (int p = 0; p < CP; p++)
                    acc[m][p] = av * wf[p] + acc[m][p];   // v_pk_fma_f32
            }
        }
    };

    loadW8(wA, wp);          // k rows 0..7
    loadA(aR0, ap);          // k 0..3
#pragma unroll 1
    for (int k = 0; k + 16 < K; k += 16) {
        loadW8(wB, wp + 8 * ws);        // rows k+8..k+15 (used 2 computeH later)
        loadA(aR1, ap + 4);             // k+4..7
        computeH(aR0, wA);              // k..k+3
        loadA(aR0, ap + 8);             // k+8..11
        computeH(aR1, wA + 4 * CG);     // k+4..7
        loadW8(wA, wp + 16 * ws);       // rows k+16..k+23 (next iter / tail)
        loadA(aR1, ap + 12);            // k+12..15
        computeH(aR0, wB);              // k+8..11
        loadA(aR0, ap + 16);            // k+16..19
        computeH(aR1, wB + 4 * CG);     // k+12..15
        wp += 16 * ws; ap += 16;
    }
    // tail: final 16 k-steps (wA = rows k..k+7, aR0 = k..k+3)
    loadW8(wB, wp + 8 * ws);
    loadA(aR1, ap + 4);
    computeH(aR0, wA);
    loadA(aR0, ap + 8);
    computeH(aR1, wA + 4 * CG);
    loadA(aR1, ap + 12);
    computeH(aR0, wB);
    computeH(aR1, wB + 4 * CG);

    v2f s2; s2.x = scale; s2.y = scale;
#pragma unroll
    for (int m = 0; m < M; m++) {
        float* op = Op + o0 + (m / SPLIT) * oHi + (m % SPLIT) * oLo;
#pragma unroll
        for (int cg = 0; cg < CG; cg++) {
            float4 r;
            v2f* rp = (v2f*)&r;
            if constexpr (ADD) {
                float4 v = *(float4*)(op + cg * 4);
                const v2f* vp = (const v2f*)&v;
                rp[0] = s2 * acc[m][cg * 2 + 0] + vp[0];
                rp[1] = s2 * acc[m][cg * 2 + 1] + vp[1];
            } else {
                rp[0] = s2 * acc[m][cg * 2 + 0];
                rp[1] = s2 * acc[m][cg * 2 + 1];
            }
            *(float4*)(op + cg * 4) = r;
        }
    }
}

// ---------------- fused kernel ----------------------------------------------
// BT=8, hb-split, 78.72 KB LDS -> 2 WG/CU (LDS-limited) REQUIRES VGPR<=128:
// measured residency cliff is 128/129 (R5: VGPR 132 -> 1 WG/CU, occupancy
// 23%->11.7%). launch_bounds(256,2) pins the cap at 128 (R0-proven); the
// allocator sheds the ~4-reg overflow via remat/cold-path spill, not the
// gemm loop state (cap-64 rounds R1/R3 were the catastrophic regime).
extern "C" __global__ __launch_bounds__(NTHR, 2)
void trans_fused(const float* __restrict__ x,
                 const float* __restrict__ L_w, const float* __restrict__ UL_w,
                 const float* __restrict__ WQ,  const float* __restrict__ WK,
                 const float* __restrict__ WVd, const float* __restrict__ WVu,
                 const float* __restrict__ WQ2, const float* __restrict__ WK2,
                 const float* __restrict__ WVd2,const float* __restrict__ WVu2,
                 const float* __restrict__ qin1,const float* __restrict__ qout1,
                 const float* __restrict__ qin2,const float* __restrict__ qout2,
                 const float* __restrict__ POSb, float* __restrict__ out)
{
    extern __shared__ float lds[];
    float* Hs = lds;                      // [80][HSTR], row = b*10 + n
    float* Qb = lds + HS_FLOATS;          // [40][QSTR], row r2 = b4*10 + n ; also G, t(lo)
    float* Kb = Qb + BUF_FLOATS;          // [40][QSTR]                     ; also t(hi)
    float* Vb = Kb + BUF_FLOATS;          // [40][QSTR] Vd
    float* Pb = Vb + BUF_FLOATS;          // [8][10][12] logits -> softmax weights
    float* Tb = Qb;                       // t: 80 rows spanning Qb+Kb

    const int tid = threadIdx.x;
    const int vtid = (tid + ((blockIdx.x & 3) << 6)) & 255;  // rotate idle windows
    const int gb0 = blockIdx.x * BT;

    // ---- Phase 0: h = x @ L_w + POS (fp32; 4-term dot, packed) ----
    for (int idx = tid; idx < NHROWS * 32; idx += NTHR) {
        int r = idx >> 5, dg = (idx & 31) << 2;
        int b = r / 10, n = r - b * 10;
        const float* xp = x + ((size_t)(gb0 + b) * TS + n) * 4;
        float4 xv = *(const float4*)xp;
        const float* xf = (const float*)&xv;
        float4 p4 = *(const float4*)(POSb + n * TD + dg);
        v2f acc0 = ((const v2f*)&p4)[0], acc1 = ((const v2f*)&p4)[1];
#pragma unroll
        for (int c = 0; c < 4; c++) {
            float4 lw = *(const float4*)(L_w + c * TD + dg);
            v2f xb; xb.x = xf[c]; xb.y = xf[c];
            acc0 = xb * ((const v2f*)&lw)[0] + acc0;
            acc1 = xb * ((const v2f*)&lw)[1] + acc1;
        }
        float4 r4;
        ((v2f*)&r4)[0] = acc0; ((v2f*)&r4)[1] = acc1;
        *(float4*)(Hs + r * HSTR + dg) = r4;
    }
    __syncthreads();

    for (int layer = 0; layer < 2; ++layer) {
        const float* pWQ  = layer ? WQ2  : WQ;
        const float* pWK  = layer ? WK2  : WK;
        const float* pWVd = layer ? WVd2 : WVd;
        const float* pWVu = layer ? WVu2 : WVu;
        const float* pqin = layer ? qin2 : qin1;
        const float* pqou = layer ? qout2 : qout1;

        for (int hb = 0; hb < 2; ++hb) {
            // batches b = hb*4 + b4; Hs rows (hb*4+b4)*10 + n
            // ---- QKV: 240 tasks = mat(3) x np(5) x cg(16); M=8 = b4(4) x (n,n+5) ----
            if (vtid < 240) {
                int p = vtid / 80, t2 = vtid % 80;
                int np = t2 >> 4, cg = t2 & 15;
                const float* Wp = (p == 0 ? pWQ : (p == 1 ? pWK : pWVd)) + cg * 4;
                float* Ob = (p == 0 ? Qb : (p == 1 ? Kb : Vb));
                gemm_f32<8, 2, 4, TD, false>(
                    Hs, (hb * 40 + np) * HSTR, 10 * HSTR, 5 * HSTR,
                    Wp, TE,
                    Ob, np * QSTR + cg * 4, 10 * QSTR, 5 * QSTR, 1.f);
            }
            __syncthreads();

            // ---- logits (fp32, 2x2 packed chains): 220 = b4(4) x 55 (i,j<=i) ----
            if (vtid < 220) {
                int b4 = vtid / 55, pr = vtid % 55;
                int i = 0, base = 0;
                while (pr >= base + i + 1) { base += i + 1; i++; }
                int j = pr - base;
                const float* qr = Qb + (b4 * 10 + i) * QSTR;
                const float* kr = Kb + (b4 * 10 + j) * QSTR;
                v2f s0 = (v2f)(0.f), s1 = (v2f)(0.f);
                for (int e = 0; e < TE; e += 8) {
                    float4 qa = *(const float4*)(qr + e);
                    float4 ka = *(const float4*)(kr + e);
                    float4 qc = *(const float4*)(qr + e + 4);
                    float4 kc = *(const float4*)(kr + e + 4);
                    s0 = ((const v2f*)&qa)[0] * ((const v2f*)&ka)[0] + s0;
                    s1 = ((const v2f*)&qa)[1] * ((const v2f*)&ka)[1] + s1;
                    s0 = ((const v2f*)&qc)[0] * ((const v2f*)&kc)[0] + s0;
                    s1 = ((const v2f*)&qc)[1] * ((const v2f*)&kc)[1] + s1;
                }
                Pb[(hb * 4 + b4) * 120 + i * 12 + j] = (s0.x + s0.y) + (s1.x + s1.y);
            }
            __syncthreads();

            // ---- softmax over keys j<=i (fp32, matches reference) ----
            if (vtid < 40) {
                int b4 = vtid / 10, i = vtid % 10;
                float* pr = Pb + (hb * 4 + b4) * 120 + i * 12;
                float m = pr[0];
#pragma unroll
                for (int j = 1; j < TS; j++) if (j <= i) m = fmaxf(m, pr[j]);
                float sum = 0.f;
#pragma unroll
                for (int j = 0; j < TS; j++) if (j <= i) { float e = expf(pr[j] - m); pr[j] = e; sum += e; }
#pragma unroll
                for (int j = 0; j < TS; j++) pr[j] = (j <= i) ? pr[j] / sum : 0.f;
            }
            __syncthreads();

            // ---- G[r2=b4*10+q][e] = sum_k P * Vd[b4*10+k][e]; into Qb (Q dead) ----
            for (int oi = vtid; oi < 40 * 16; oi += NTHR) {
                int rr = oi >> 4, e4 = (oi & 15) * 4;
                int b4 = rr / 10, q = rr - b4 * 10;
                const float* pp = Pb + (hb * 4 + b4) * 120 + q * 12;
                v2f g0 = (v2f)(0.f), g1 = (v2f)(0.f);
#pragma unroll
                for (int k = 0; k < TS; k++) {
                    float p = pp[k];
                    v2f pv; pv.x = p; pv.y = p;
                    float4 v = *(const float4*)(Vb + (b4 * 10 + k) * QSTR + e4);
                    g0 = pv * ((const v2f*)&v)[0] + g0;
                    g1 = pv * ((const v2f*)&v)[1] + g1;
                }
                float4 g;
                ((v2f*)&g)[0] = g0; ((v2f*)&g)[1] = g1;
                *(float4*)(Qb + rr * QSTR + e4) = g;
            }
            __syncthreads();

            // ---- DE: Hs(half) += invsqrt10 * G @ WVu ----
            // 256 tasks exactly: b4(4) x qp(2) x cg(32); M=5 contiguous q rows.
            {
                int b4 = vtid >> 6, t2 = vtid & 63;
                int qp = t2 >> 5, cg = t2 & 31;
                gemm_f32<5, 5, 4, TE, true>(
                    Qb, (b4 * 10 + qp * 5) * QSTR, 0, QSTR,
                    pWVu + cg * 4, TD,
                    Hs, (hb * 40 + b4 * 10 + qp * 5) * HSTR + cg * 4, 0, HSTR,
                    INVSQRT10);
            }
            __syncthreads();
        } // hb

        // ---- ques-in: t[80][64] = Hs @ quesin[n]; 160 = n(10) x cg(16), M=8 over b ----
        if (vtid < 160) {
            int n = vtid >> 4, cg = vtid & 15;
            gemm_f32<8, 1, 4, TD, false>(
                Hs, n * HSTR, 10 * HSTR, 0,
                pqin + (size_t)n * TD * TE + cg * 4, TE,
                Tb, n * QSTR + cg * 4, 10 * QSTR, 0, 1.f);
        }
        __syncthreads();

        // ---- ques-out: Hs = t @ quesout[n]; 320 = n(10) x cg(32), M=8 C=4 ----
        for (int task = vtid; task < 320; task += NTHR) {
            int n = task >> 5, cg = task & 31;
            gemm_f32<8, 1, 4, TE, false>(
                Tb, n * QSTR, 10 * QSTR, 0,
                pqou + (size_t)n * TE * TD + cg * 4, TD,
                Hs, n * HSTR + cg * 4, 10 * HSTR, 0, 1.f);
        }
        __syncthreads();
    } // layer

    // ---- out = Hs @ UL_w : 320 outs, rotated grid-stride ----
    for (int idx = vtid; idx < NHROWS * 4; idx += NTHR) {
        int r = idx >> 2, c = idx & 3;
        int b = r / 10, n = r - b * 10;
        const float* hr = Hs + r * HSTR;
        float acc = 0.f;
        for (int d = 0; d < TD; d += 4) {
            float4 h4 = *(const float4*)(hr + d);
            acc = fmaf(h4.x, UL_w[(d + 0) * 4 + c], acc);
            acc = fmaf(h4.y, UL_w[(d + 1) * 4 + c], acc);
            acc = fmaf(h4.z, UL_w[(d + 2) * 4 + c], acc);
            acc = fmaf(h4.w, UL_w[(d + 3) * 4 + c], acc);
        }
        out[((size_t)(gb0 + b) * TS + n) * 4 + c] = acc;
    }
}

// ---------------- host launch -----------------------------------------------
extern "C" void kernel_launch(void* const* d_in, const int* in_sizes, int n_in,
                              void* d_out, int out_size, void* d_ws, size_t ws_size,
                              hipStream_t stream) {
    const float* x    = (const float*)d_in[0];
    const float* L_w  = (const float*)d_in[1];
    const float* UL_w = (const float*)d_in[2];
    const float* WQ   = (const float*)d_in[3];
    const float* WK   = (const float*)d_in[4];
    const float* WVd  = (const float*)d_in[5];
    const float* WVu  = (const float*)d_in[6];
    const float* WQ2  = (const float*)d_in[7];
    const float* WK2  = (const float*)d_in[8];
    const float* WVd2 = (const float*)d_in[9];
    const float* WVu2 = (const float*)d_in[10];
    const float* qin1 = (const float*)d_in[11];
    const float* qout1= (const float*)d_in[12];
    const float* qin2 = (const float*)d_in[13];
    const float* qout2= (const float*)d_in[14];
    float* out = (float*)d_out;
    float* POSb = (float*)d_ws;

    int B = in_sizes[0] / (TS * 4);
    size_t lds_bytes = (size_t)LDS_FLOATS * sizeof(float);

    (void)hipFuncSetAttribute((const void*)trans_fused,
                              hipFuncAttributeMaxDynamicSharedMemorySize,
                              (int)lds_bytes);

    pos_kernel<<<dim3(1), dim3(256), 0, stream>>>(POSb);
    trans_fused<<<dim3(B / BT), dim3(NTHR), lds_bytes, stream>>>(
        x, L_w, UL_w, WQ, WK, WVd, WVu, WQ2, WK2, WVd2, WVu2,
        qin1, qout1, qin2, qout2, POSb, out);
}